// Round 1
// 67.518 us; speedup vs baseline: 1.0426x; 1.0426x over previous
//
#include <hip/hip_runtime.h>

// pAUC loss, single-dispatch, REDUNDANT-SELECT version, round 6:
//   bce(i,j) = -log(clip(sigmoid(pos_i - neg_j), 1e-6, 1-1e-6))
//   out = sum_i topk_j(bce, K=512) / (N_pos * N_neg)
// bce monotone in neg_j => every row's top-K = the K largest negatives.
// Every block runs the radix select locally (identical deterministic result).
// R6 changes vs R5-redundant:
//  - pass-0 histogram privatized 8x (per wave-pair): normal-distributed keys
//    concentrate ~85% of mass into ~100 hot exponent bins -> same-address LDS
//    RMW serialization was the dominant cost; privatization cuts depth 8x.
//  - scatter via ballot compaction: 1 wave-atomic per key slot instead of
//    ~512 lane-serialized atomics; ties filled directly with decode(T).
//  - GRID 128->256: all 256 CUs (select wall unchanged, BCE rows halved).
//  - pos rows staged to LDS, load issued at kernel entry (hides cold HBM
//    latency under select); break-free BCE inner loop.

#define TOPK 512
#define BT   1024
#define GRID 256
#define EPT  16                  // BT * EPT = 16384 >= n_neg
#define NHIST 8                  // privatized pass-0 histograms (wave pairs)
#define POS_LDS 1024
#define BCE_LO 1.0000005e-6f     // -log(1-1e-6)
#define BCE_HI 13.8155106f       // -log(1e-6)

__global__ __launch_bounds__(BT) void pauc_fused_kernel(
    const float* __restrict__ neg, int n_neg,
    const float* __restrict__ pos, int n_pos,
    float* __restrict__ out, float inv_denom, int k,
    float* __restrict__ partials, unsigned int* __restrict__ done) {
    const int tid  = threadIdx.x;
    const int lane = tid & 63;
    const int wv   = tid >> 6;

    __shared__ unsigned int hist[NHIST * 1024];   // 32 KB
    __shared__ float        s_topk[TOPK];
    __shared__ float        s_pos[POS_LDS];
    __shared__ unsigned int wtot[16], wsuf[16];
    __shared__ unsigned int bc_digit, bc_kk, bc_cd;
    __shared__ unsigned int out_gt;
    __shared__ float        s_red[BT / 64];

    const int rows_pb = (n_pos + GRID - 1) / GRID;      // 32 in harness
    const bool pos_in_lds = rows_pb <= POS_LDS;

    // -------- issue pos prefetch FIRST (latency hides under select) --------
    float pv0 = 0.0f;
    const int prow = blockIdx.x * rows_pb + tid;
    const bool pv0_v = pos_in_lds && (tid < rows_pb) && (prow < n_pos);
    if (pv0_v) pv0 = pos[prow];

    // ---------------- load all keys (every block, redundant) ----------------
    unsigned int keys[EPT];
    if (n_neg == BT * EPT) {                // harness case: float4 loads
        const float4* n4 = (const float4*)neg;
        #pragma unroll
        for (int t = 0; t < EPT / 4; ++t) {
            float4 v = n4[t * BT + tid];
            unsigned int u0 = __float_as_uint(v.x), u1 = __float_as_uint(v.y);
            unsigned int u2 = __float_as_uint(v.z), u3 = __float_as_uint(v.w);
            keys[4*t+0] = u0 ^ (0x80000000u | (unsigned)((int)u0 >> 31));
            keys[4*t+1] = u1 ^ (0x80000000u | (unsigned)((int)u1 >> 31));
            keys[4*t+2] = u2 ^ (0x80000000u | (unsigned)((int)u2 >> 31));
            keys[4*t+3] = u3 ^ (0x80000000u | (unsigned)((int)u3 >> 31));
        }
    } else {
        #pragma unroll
        for (int t = 0; t < EPT; ++t) {
            int i = t * BT + tid;
            unsigned int key = 0u;          // pad = smallest key
            if (i < n_neg) {
                unsigned int u = __float_as_uint(neg[i]);
                key = u ^ (0x80000000u | (unsigned)((int)u >> 31));
            }
            keys[t] = key;
        }
    }

    // zero privatized histograms (independent of in-flight loads)
    #pragma unroll
    for (int i = 0; i < NHIST; ++i) hist[(i << 10) + tid] = 0u;
    if (pos_in_lds && tid < rows_pb) s_pos[tid] = pv0_v ? pv0 : 0.0f;
    __syncthreads();

    // ---------------- exact top-k: radix select (10/10/10/2), early-exit ----
    const int      shifts[4] = {22, 12, 2, 0};
    const unsigned nbv[4]    = {1024u, 1024u, 1024u, 4u};
    unsigned int prefix = 0u, pmask = 0u, kk = (unsigned)k;
    for (int pass = 0; pass < 4; ++pass) {
        const int shift      = shifts[pass];
        const unsigned nb    = nbv[pass];
        const unsigned dmask = nb - 1u;
        if (pass > 0) {                      // pass 0 bins zeroed above
            if (tid < (int)nb) hist[tid] = 0u;
            __syncthreads();
        }
        if (pass == 0) {
            // privatized histogram: wave-pair wv>>1 owns hist[(wv>>1)<<10 ..]
            unsigned int* h = &hist[(unsigned)(wv >> 1) << 10];
            #pragma unroll
            for (int t = 0; t < EPT; ++t)
                atomicAdd(&h[keys[t] >> 22], 1u);
        } else {
            #pragma unroll
            for (int t = 0; t < EPT; ++t) {
                unsigned int ky = keys[t];
                if ((ky & pmask) == prefix)
                    atomicAdd(&hist[(ky >> shift) & dmask], 1u);
            }
        }
        __syncthreads();
        // bin count for this tid (merge the 8 private copies on pass 0)
        unsigned int c;
        if (pass == 0) {
            c = 0u;
            #pragma unroll
            for (int i = 0; i < NHIST; ++i) c += hist[(i << 10) + tid];
        } else {
            c = (tid < (int)nb) ? hist[tid] : 0u;
        }
        // register suffix scan: suf[d] = # participants with digit >= d
        unsigned int part = c;
        #pragma unroll
        for (int off = 1; off < 64; off <<= 1) {
            unsigned int v = __shfl_down(part, off, 64);
            if (lane + off < 64) part += v;
        }
        if (lane == 0) wtot[wv] = part;
        __syncthreads();
        if (wv == 0) {                       // wave 0: suffix-scan wave totals
            unsigned int wval = (lane < 16) ? wtot[lane] : 0u;
            unsigned int incl = wval;
            #pragma unroll
            for (int off = 1; off < 16; off <<= 1) {
                unsigned int v = __shfl_down(incl, off, 64);
                if (lane + off < 64) incl += v;
            }
            if (lane < 16) wsuf[lane] = incl - wval;   // exclusive suffix
        }
        __syncthreads();
        unsigned int suf = part + wsuf[wv];
        unsigned int s_next = __shfl_down(suf, 1, 64);
        if (lane == 63) s_next = wsuf[wv];   // = suf[tid+1] across waves
        if (tid < (int)nb && suf >= kk && s_next < kk) {
            bc_digit = (unsigned)tid;
            bc_kk    = kk - s_next;
            bc_cd    = c;                    // chosen bin's count
        }
        __syncthreads();
        unsigned int newpref = prefix | (bc_digit << shift);
        if (pass < 3 && bc_kk == bc_cd && newpref != 0u) {
            // whole bin selected: T = bin lower boundary - 1, no ties
            prefix = newpref - 1u;
            kk = 0u;
            break;
        }
        prefix = newpref;
        kk = bc_kk;
        pmask |= dmask << shift;
    }

    // ---------------- scatter top-k into LDS (ballot compaction) ------------
    const unsigned int T = prefix;          // exact threshold key
    if (tid == 0) out_gt = 0u;
    __syncthreads();
    const unsigned int n_gt = (unsigned)k - kk;   // # keys strictly > T
    #pragma unroll
    for (int t = 0; t < EPT; ++t) {
        unsigned int ky = keys[t];
        bool g = ky > T;
        unsigned long long m = __ballot(g);
        if (m) {                              // wave-uniform
            unsigned int cnt = (unsigned)__popcll(m);
            unsigned int base;
            if (lane == 0) base = atomicAdd(&out_gt, cnt);
            base = __shfl(base, 0, 64);
            if (g) {
                unsigned int idx = base +
                    (unsigned)__popcll(m & ((1ull << lane) - 1ull));
                unsigned int u = (ky >> 31) ? (ky ^ 0x80000000u)
                                            : (ky ^ 0xFFFFFFFFu);
                s_topk[idx] = __uint_as_float(u);
            }
        }
    }
    // ties: all ==T keys decode to the same float -> write kk copies directly
    if (tid < (int)kk) {
        unsigned int u = (T >> 31) ? (T ^ 0x80000000u) : (T ^ 0xFFFFFFFFu);
        s_topk[n_gt + tid] = __uint_as_float(u);
    }
    __syncthreads();

    // -------- bce partial sum: 1 col/thread, 2 row-groups from LDS ----------
    const int col = tid & (TOPK - 1);
    const int rg  = tid >> 9;                          // 0 or 1
    const bool cv = col < k;
    const float tv = cv ? s_topk[col] : 0.0f;
    const int rpg  = (rows_pb + (BT / TOPK) - 1) / (BT / TOPK);  // 16
    const int rbase = blockIdx.x * rows_pb + rg * rpg;
    int lim = n_pos - rbase;
    int lmax = rows_pb - rg * rpg;
    if (lim > lmax) lim = lmax;
    if (lim > rpg)  lim = rpg;
    if (lim < 0)    lim = 0;
    float acc = 0.0f;
    if (pos_in_lds) {
        const float* sp = &s_pos[rg * rpg];
        #pragma unroll 4
        for (int r = 0; r < lim; ++r) {
            float pv = sp[r];
            // -log(clip(sigmoid(pv - tv))) = clamp(log(1 + exp(tv - pv)))
            float b = __logf(1.0f + __expf(tv - pv));
            b = fminf(fmaxf(b, BCE_LO), BCE_HI);
            acc += b;
        }
    } else {
        for (int r = 0; r < lim; ++r) {
            float pv = pos[rbase + r];
            float b = __logf(1.0f + __expf(tv - pv));
            b = fminf(fmaxf(b, BCE_LO), BCE_HI);
            acc += b;
        }
    }
    if (!cv) acc = 0.0f;
    #pragma unroll
    for (int off = 32; off > 0; off >>= 1) acc += __shfl_down(acc, off, 64);
    if (lane == 0) s_red[wv] = acc;
    __syncthreads();
    if (tid == 0) {
        float t = 0.0f;
        #pragma unroll
        for (int w = 0; w < BT / 64; ++w) t += s_red[w];
        __hip_atomic_store(&partials[blockIdx.x], t,
                           __ATOMIC_RELAXED, __HIP_MEMORY_SCOPE_AGENT);
        __hip_atomic_store(&done[blockIdx.x], 1u,
                           __ATOMIC_RELEASE, __HIP_MEMORY_SCOPE_AGENT);
    }

    // ---------------- block 0: gather the 256 partials ----------------------
    if (blockIdx.x == 0) {
        float a = 0.0f;
        if (tid < GRID) {
            while (__hip_atomic_load(&done[tid], __ATOMIC_RELAXED,
                                     __HIP_MEMORY_SCOPE_AGENT) != 1u)
                __builtin_amdgcn_s_sleep(1);
            __builtin_amdgcn_fence(__ATOMIC_ACQUIRE, "agent");
            a = __hip_atomic_load(&partials[tid], __ATOMIC_RELAXED,
                                  __HIP_MEMORY_SCOPE_AGENT);
        }
        #pragma unroll
        for (int off = 32; off > 0; off >>= 1) a += __shfl_down(a, off, 64);
        if (lane == 0) s_red[wv] = a;
        __syncthreads();
        if (tid == 0) {
            float t = 0.0f;
            #pragma unroll
            for (int w = 0; w < BT / 64; ++w) t += s_red[w];
            out[0] = t * inv_denom;
        }
    }
}

extern "C" void kernel_launch(void* const* d_in, const int* in_sizes, int n_in,
                              void* d_out, int out_size, void* d_ws, size_t ws_size,
                              hipStream_t stream) {
    const float* neg = (const float*)d_in[0];   // score_neg, 16384
    const float* pos = (const float*)d_in[1];   // score_pos, 8192
    const int n_neg = in_sizes[0];
    const int n_pos = in_sizes[1];
    float* out = (float*)d_out;
    float* ws  = (float*)d_ws;

    int k = TOPK; if (k > n_neg) k = n_neg;
    float*        partials = ws;                             // [0, GRID)
    unsigned int* done     = (unsigned int*)(ws + GRID);     // [GRID, 2*GRID)

    const float inv_denom = (float)(1.0 / ((double)n_pos * (double)n_neg));
    pauc_fused_kernel<<<GRID, BT, 0, stream>>>(
        neg, n_neg, pos, n_pos, out, inv_denom, k, partials, done);
}